// Round 1
// 234.384 us; speedup vs baseline: 1.0654x; 1.0654x over previous
//
#include <hip/hip_runtime.h>

// ROUND 11 — attention scheduling fix:
// (1) LPT "snake" block remap: old qt = blockIdx.x aliased mod-32 with
//     round-robin CU assignment, putting 3 SAME-qt blocks on each CU
//     (makespan 96 tile-iters; CU with qt=0 did 3 and idled). Snake maps
//     linear id n -> item i = {m, 511-m, 512+m} so the 3 co-resident
//     blocks' qt sum is ~47 (range 42..51). Perf-only, correctness-neutral.
// (2) T14 async-STAGE: K/V/mask for tile t+1 are global-loaded into regs
//     right AFTER the pre-compute barrier, so HBM/L2 latency hides under
//     QK^T+softmax+PV; regs -> LDS write happens next iteration.
// (3) s_setprio(1) around MFMA clusters (T5).
// GEMMs / transpose unchanged from round 10.
// ws (bf16): qh[3145728] kh[3145728] vh[3145728] wt[4*589824] = 23.6 MB.
// O overwrites qh in place after attention.

#define NEGV (-10000.0f)

typedef __attribute__((ext_vector_type(8))) short v8s;
typedef __attribute__((ext_vector_type(4))) float v4f;
typedef __attribute__((ext_vector_type(8))) unsigned short v8u;

__device__ __forceinline__ unsigned short f2bf(float f) {
  unsigned int u = __float_as_uint(f);
  u += 0x7FFFu + ((u >> 16) & 1u);   // RNE
  return (unsigned short)(u >> 16);
}

// ---------------------------------------------------------------- W transpose
// W fp32 [k][n] -> Wt bf16 [n][k]; 4 matrices via z.
__global__ __launch_bounds__(256) void transpose_w(
    const float* __restrict__ w0, const float* __restrict__ w1,
    const float* __restrict__ w2, const float* __restrict__ w3,
    unsigned short* __restrict__ t0, unsigned short* __restrict__ t1,
    unsigned short* __restrict__ t2, unsigned short* __restrict__ t3) {
  const float* w; unsigned short* t;
  switch (blockIdx.z) {
    case 0: w = w0; t = t0; break;
    case 1: w = w1; t = t1; break;
    case 2: w = w2; t = t2; break;
    default: w = w3; t = t3; break;
  }
  __shared__ unsigned short tile[32][33];
  const int tx = threadIdx.x & 31, ty = threadIdx.x >> 5;
  const int x0 = blockIdx.x * 32, y0 = blockIdx.y * 32;
#pragma unroll
  for (int j = 0; j < 4; j++)
    tile[ty + j * 8][tx] = f2bf(w[(size_t)(y0 + ty + j * 8) * 768 + x0 + tx]);
  __syncthreads();
#pragma unroll
  for (int j = 0; j < 4; j++)
    t[(size_t)(x0 + ty + j * 8) * 768 + y0 + tx] = tile[tx][ty + j * 8];
}

// ---------------------------------------------------------------- GEMM core
// 128x128 tile, 4 waves 2x2, 16x16x32 bf16 MFMA, BK=32.
// A: fp32 row-major (converted in regs) or bf16 head-major.
// B: bf16 Wt[n][k] -> contiguous uint4 + ds_write_b128.
// C: bf16 head-major or fp32 row-major (d_out).
template <bool ABF16HEAD, bool CF32ROW>
__device__ __forceinline__ void gemm_core(const void* __restrict__ A,
                                          const unsigned short* __restrict__ Wt,
                                          void* __restrict__ C) {
  const int tid = threadIdx.x;
  const int wave = tid >> 6, lane = tid & 63;
  const int quad = lane >> 4, l16 = lane & 15;
  const int wm = wave >> 1, wn = wave & 1;
  const int bm = blockIdx.x * 128, bn = blockIdx.y * 128;

  __shared__ __align__(16) unsigned short As[128 * 32];
  __shared__ __align__(16) unsigned short Bs[128 * 32];

  v4f acc[4][4];
#pragma unroll
  for (int i = 0; i < 4; i++)
#pragma unroll
    for (int j = 0; j < 4; j++) acc[i][j] = (v4f){0.f, 0.f, 0.f, 0.f};

  for (int kt = 0; kt < 24; kt++) {
    __syncthreads();
#pragma unroll
    for (int p = 0; p < 2; p++) {
      int idx = p * 256 + tid;
      int r = idx >> 2, c0 = (idx & 3) << 3;
      // ---- A staging: As[r][k] = A[bm+r][kt*32+k]
      int rg = bm + r, c = kt * 32 + c0;
      if (ABF16HEAD) {
        size_t aoff = ((size_t)((rg >> 11) * 12 + (c >> 6)) * 2048 +
                       (rg & 2047)) * 64 + (c & 63);
        *(uint4*)&As[r * 32 + c0] =
            *(const uint4*)((const unsigned short*)A + aoff);
      } else {
        const float* Af = (const float*)A;
        size_t aoff = (size_t)rg * 768 + c;
        float4 x0 = *(const float4*)(Af + aoff);
        float4 x1 = *(const float4*)(Af + aoff + 4);
        v8u tmp;
        tmp[0] = f2bf(x0.x); tmp[1] = f2bf(x0.y);
        tmp[2] = f2bf(x0.z); tmp[3] = f2bf(x0.w);
        tmp[4] = f2bf(x1.x); tmp[5] = f2bf(x1.y);
        tmp[6] = f2bf(x1.z); tmp[7] = f2bf(x1.w);
        *(uint4*)&As[r * 32 + c0] = *(uint4*)&tmp;
      }
      // ---- B staging: Bs[n][k] = Wt[bn+n][kt*32+k] (contiguous 16B)
      *(uint4*)&Bs[r * 32 + c0] =
          *(const uint4*)&Wt[(size_t)(bn + r) * 768 + c];
    }
    __syncthreads();

    v8s aF[4], bF[4];
#pragma unroll
    for (int mt = 0; mt < 4; mt++)
      aF[mt] = *(const v8s*)&As[(wm * 64 + mt * 16 + l16) * 32 + quad * 8];
#pragma unroll
    for (int nt = 0; nt < 4; nt++)
      bF[nt] = *(const v8s*)&Bs[(wn * 64 + nt * 16 + l16) * 32 + quad * 8];
#pragma unroll
    for (int mt = 0; mt < 4; mt++)
#pragma unroll
      for (int nt = 0; nt < 4; nt++)
        acc[mt][nt] = __builtin_amdgcn_mfma_f32_16x16x32_bf16(
            aF[mt], bF[nt], acc[mt][nt], 0, 0, 0);
  }

  // epilogue: C/D layout row(m) = quad*4+i, col(n) = l16
#pragma unroll
  for (int mt = 0; mt < 4; mt++) {
#pragma unroll
    for (int i = 0; i < 4; i++) {
      int row = bm + wm * 64 + mt * 16 + quad * 4 + i;
#pragma unroll
      for (int nt = 0; nt < 4; nt++) {
        int col = bn + wn * 64 + nt * 16 + l16;
        if (CF32ROW) {
          ((float*)C)[(size_t)row * 768 + col] = acc[mt][nt][i];
        } else {
          size_t off = ((size_t)((row >> 11) * 12 + (col >> 6)) * 2048 +
                        (row & 2047)) * 64 + (col & 63);
          ((unsigned short*)C)[off] = f2bf(acc[mt][nt][i]);
        }
      }
    }
  }
}

__global__ __launch_bounds__(256) void gemm_qkv(
    const float* __restrict__ xq, const float* __restrict__ xk,
    const float* __restrict__ xv, const unsigned short* __restrict__ wqt,
    const unsigned short* __restrict__ wkt, const unsigned short* __restrict__ wvt,
    unsigned short* __restrict__ qh, unsigned short* __restrict__ kh,
    unsigned short* __restrict__ vh) {
  const float* A; const unsigned short* Wt; unsigned short* C;
  switch (blockIdx.z) {
    case 0: A = xq; Wt = wqt; C = qh; break;
    case 1: A = xk; Wt = wkt; C = kh; break;
    default: A = xv; Wt = wvt; C = vh; break;
  }
  gemm_core<false, false>((const void*)A, Wt, (void*)C);
}

__global__ __launch_bounds__(256) void gemm_o(
    const unsigned short* __restrict__ oat, const unsigned short* __restrict__ wot,
    float* __restrict__ out) {
  gemm_core<true, true>((const void*)oat, wot, (void*)out);
}

// ---------------------------------------------------------------- attention
// grid (32, 24) = 768 linear blocks. LPT snake remap inside (see header).
// 4 waves x 16 q-rows. Causal tiles kt=0..qt always; future tiles only if
// some row's visible window was fully padded (m_i = -10000): for rows with
// m_i > -5000, future scores <= -9995 -> exp underflows to 0 exactly and
// max is unchanged, so skipping is bit-exact.
__global__ __launch_bounds__(256) void attn_kernel(
    const unsigned short* __restrict__ qh, const unsigned short* __restrict__ kh,
    const unsigned short* __restrict__ vh, const int* __restrict__ attn_mask,
    const int* __restrict__ mask_future, unsigned short* __restrict__ o) {
  const int S = 2048, HD = 64, NH = 12;

  // ---- LPT snake remap ------------------------------------------------
  // Work per q-tile is qt+1 k-tiles. All 768 blocks are co-resident; under
  // round-robin dispatch blocks n, n+256, n+512 share a CU. Old qt = n%32
  // gave each CU 3 identical-qt blocks (worst CU: 96 iters). Snake:
  //   tier 0: item m      (qt 31..21, heavy)
  //   tier 1: item 511-m  (qt 21..31 reversed)
  //   tier 2: item 512+m  (qt 10..0, light)
  // -> per-CU iter sums in [45..54] vs balanced 49.5.
  const int nlin = blockIdx.x + 32 * blockIdx.y;        // grid (32,24)
  const int m_ = nlin & 255, t_ = nlin >> 8;
  const int i_ = (t_ == 1) ? (511 - m_) : (t_ * 256 + m_);
  const int qt = 31 - i_ / 24;
  const int bh = i_ - (i_ / 24) * 24;
  const int b = bh / NH, h = bh % NH;

  const int tid = threadIdx.x;
  const int wave = tid >> 6, lane = tid & 63;
  const int quad = lane >> 4, l16 = lane & 15;

  __shared__ __align__(16) unsigned short Ks[64 * 72];
  __shared__ __align__(16) unsigned short Vt[64 * 72];
  __shared__ __align__(16) unsigned short Ps[4][16 * 72];
  __shared__ int Ms[64];
  __shared__ int s_flag;

  const size_t head_off = (size_t)(b * NH + h) * S * HD;
  const unsigned short* Kb = kh + head_off;
  const unsigned short* Vb = vh + head_off;

  const int mf = mask_future[0];
  if (tid == 0) s_flag = 0;

  const int qrowA = qt * 64 + wave * 16 + l16;
  v8s aQ[2];
  {
    const unsigned short* qp = qh + head_off + (size_t)qrowA * HD + quad * 8;
    aQ[0] = *(const v8s*)(qp);
    aQ[1] = *(const v8s*)(qp + 32);
  }
  const int qbase = qt * 64 + wave * 16 + quad * 4;

  float m_i[4], l_i[4];
  v4f accO[4];
#pragma unroll
  for (int i = 0; i < 4; i++) { m_i[i] = -1e30f; l_i[i] = 0.f; }
#pragma unroll
  for (int dt = 0; dt < 4; dt++) accO[dt] = (v4f){0.f, 0.f, 0.f, 0.f};

  const int kt_causal = mf ? qt : (S / 64 - 1);  // last always-needed tile

  // ---- T14 register prefetch state (K: 2x uint4, V: 2x uint4, mask) ----
  uint4 pk0, pk1, pv0, pv1;
  int pm = 0;
  bool have = false;

  auto prefetch = [&](int kt) {
    const uint4* srck = (const uint4*)(Kb + (size_t)kt * 64 * HD);
    const uint4* srcv = (const uint4*)(Vb + (size_t)kt * 64 * HD);
    pk0 = srck[tid];
    pk1 = srck[256 + tid];
    pv0 = srcv[tid];
    pv1 = srcv[256 + tid];
    if (tid < 64) pm = attn_mask[b * S + kt * 64 + tid];
  };

  auto stage = [&]() {
#pragma unroll
    for (int p = 0; p < 2; p++) {
      int idx = p * 256 + tid;
      int r = idx >> 3;
      int c0 = (idx & 7) << 3;
      *(uint4*)&Ks[r * 72 + c0] = p ? pk1 : pk0;
      v8u vv;
      *(uint4*)&vv = p ? pv1 : pv0;
#pragma unroll
      for (int i = 0; i < 8; i++) {
        int d = c0 + i;
        int scol = (r + c0) & 63;  // diagonal swizzle (shift == c0)
        Vt[d * 72 + scol] = vv[i];
      }
    }
    if (tid < 64) Ms[tid] = pm;
  };

  for (int phase = 0; phase < 2; phase++) {
    int kt_lo, kt_hi;
    if (phase == 0) { kt_lo = 0; kt_hi = kt_causal; }
    else {
      // fallback only if some row's visible window was fully padded
      bool need = (m_i[0] < -5000.f) || (m_i[1] < -5000.f) ||
                  (m_i[2] < -5000.f) || (m_i[3] < -5000.f);
      if (need) s_flag = 1;  // benign race (0->1)
      __syncthreads();
      if (!s_flag) break;
      kt_lo = kt_causal + 1; kt_hi = S / 64 - 1;
    }
    for (int kt = kt_lo; kt <= kt_hi; kt++) {
      if (!have) prefetch(kt);  // cold start of a phase only
      __syncthreads();          // prev compute done; LDS free
      stage();                  // regs -> LDS (K linear, V swizzled, mask)
      __syncthreads();

      // Issue NEXT tile's global loads now: they complete during compute
      // below and are waited at the next iteration's barrier.
      {
        int ktn = -1;
        if (kt < kt_hi) ktn = kt + 1;
        else if (phase == 0 && mf && kt_causal < S / 64 - 1)
          ktn = kt_causal + 1;  // speculative for padded-row fallback phase
        if (ktn >= 0) { prefetch(ktn); have = true; }
        else have = false;
      }

      // S = Q K^T
      v4f sc[4];
      __builtin_amdgcn_s_setprio(1);
#pragma unroll
      for (int nt = 0; nt < 4; nt++) {
        const unsigned short* kp = &Ks[(nt * 16 + l16) * 72 + quad * 8];
        v8s b0 = *(const v8s*)kp;
        v8s b1 = *(const v8s*)(kp + 32);
        v4f z = (v4f){0.f, 0.f, 0.f, 0.f};
        z = __builtin_amdgcn_mfma_f32_16x16x32_bf16(aQ[0], b0, z, 0, 0, 0);
        z = __builtin_amdgcn_mfma_f32_16x16x32_bf16(aQ[1], b1, z, 0, 0, 0);
        sc[nt] = z;
      }
      __builtin_amdgcn_s_setprio(0);

      // scale + causal (additive) + padding (replace) — exact ref semantics
#pragma unroll
      for (int nt = 0; nt < 4; nt++) {
        int key = kt * 64 + nt * 16 + l16;
        bool pad = (Ms[nt * 16 + l16] == 0);
#pragma unroll
        for (int i = 0; i < 4; i++) {
          float v = sc[nt][i] * 0.125f;
          v += (mf && (key > qbase + i)) ? NEGV : 0.f;
          v = pad ? NEGV : v;
          sc[nt][i] = v;
        }
      }

      // online softmax
#pragma unroll
      for (int i = 0; i < 4; i++) {
        float mx = fmaxf(fmaxf(sc[0][i], sc[1][i]), fmaxf(sc[2][i], sc[3][i]));
        mx = fmaxf(mx, __shfl_xor(mx, 1));
        mx = fmaxf(mx, __shfl_xor(mx, 2));
        mx = fmaxf(mx, __shfl_xor(mx, 4));
        mx = fmaxf(mx, __shfl_xor(mx, 8));
        float mnew = fmaxf(m_i[i], mx);
        float alpha = __expf(m_i[i] - mnew);
        m_i[i] = mnew;
        float rs = 0.f;
#pragma unroll
        for (int nt = 0; nt < 4; nt++) {
          float p = __expf(sc[nt][i] - mnew);
          sc[nt][i] = p;
          rs += p;
        }
        rs += __shfl_xor(rs, 1);
        rs += __shfl_xor(rs, 2);
        rs += __shfl_xor(rs, 4);
        rs += __shfl_xor(rs, 8);
        l_i[i] = l_i[i] * alpha + rs;
#pragma unroll
        for (int dt = 0; dt < 4; dt++) accO[dt][i] *= alpha;
      }

      // P: C-layout regs -> per-wave LDS -> A-layout frags
#pragma unroll
      for (int nt = 0; nt < 4; nt++)
#pragma unroll
        for (int i = 0; i < 4; i++)
          Ps[wave][(quad * 4 + i) * 72 + nt * 16 + l16] = f2bf(sc[nt][i]);

      __builtin_amdgcn_s_setprio(1);
#pragma unroll
      for (int ks = 0; ks < 2; ks++) {
        v8s aP = *(const v8s*)&Ps[wave][l16 * 72 + ks * 32 + quad * 8];
#pragma unroll
        for (int dt = 0; dt < 4; dt++) {
          int d = dt * 16 + l16;
          int scol = ((ks * 32 + quad * 8) + ((d >> 3) << 3)) & 63;
          v8s bV = *(const v8s*)&Vt[d * 72 + scol];
          accO[dt] =
              __builtin_amdgcn_mfma_f32_16x16x32_bf16(aP, bV, accO[dt], 0, 0, 0);
        }
      }
      __builtin_amdgcn_s_setprio(0);
    }
    if (phase == 0) __syncthreads();  // all waves done before flag vote
  }

  // normalize + store O bf16 head-major over own Q region (in place)
#pragma unroll
  for (int i = 0; i < 4; i++) {
    float inv = 1.f / l_i[i];
    int qr = qbase + i;
    size_t base = head_off + (size_t)qr * HD;
#pragma unroll
    for (int dt = 0; dt < 4; dt++)
      o[base + dt * 16 + l16] = f2bf(accO[dt][i] * inv);
  }
}

// ---------------------------------------------------------------- launch
extern "C" void kernel_launch(void* const* d_in, const int* in_sizes, int n_in,
                              void* d_out, int out_size, void* d_ws, size_t ws_size,
                              hipStream_t stream) {
  const float* q  = (const float*)d_in[0];
  const float* k  = (const float*)d_in[1];
  const float* v  = (const float*)d_in[2];
  const int* amask = (const int*)d_in[3];
  const float* Wq = (const float*)d_in[4];
  const float* Wk = (const float*)d_in[5];
  const float* Wv = (const float*)d_in[6];
  const float* Wo = (const float*)d_in[7];
  const int* mf  = (const int*)d_in[8];
  float* out = (float*)d_out;

  unsigned short* ws = (unsigned short*)d_ws;
  unsigned short* qh = ws;                  // O overwrites qh after attention
  unsigned short* kh = qh + 3145728;
  unsigned short* vh = kh + 3145728;
  unsigned short* wqt = vh + 3145728;
  unsigned short* wkt = wqt + 589824;
  unsigned short* wvt = wkt + 589824;
  unsigned short* wot = wvt + 589824;

  transpose_w<<<dim3(24, 24, 4), 256, 0, stream>>>(Wq, Wk, Wv, Wo,
                                                   wqt, wkt, wvt, wot);
  gemm_qkv<<<dim3(32, 6, 3), 256, 0, stream>>>(q, k, v, wqt, wkt, wvt,
                                               qh, kh, vh);
  attn_kernel<<<dim3(32, 24), 256, 0, stream>>>(qh, kh, vh, amask, mf, qh);
  gemm_o<<<dim3(32, 6), 256, 0, stream>>>(qh, wot, out);
}

// Round 2
// 221.529 us; speedup vs baseline: 1.1272x; 1.0580x over previous
//
#include <hip/hip_runtime.h>

// ROUND 12 — attention LDS-pipe diet (was 84 DS ops/wave-iter -> 46):
// (1) row-sum l_i via extra MFMA with all-ones B-frag (removes 16 shuffles);
// (2) row-max via packed v_pk_max_f16 (8 shuffles instead of 16; softmax is
//     invariant to the exact max as long as it's row-uniform);
// (3) V pre-transposed per head to vht[d][s] (new transpose_vh kernel writing
//     into the dead d_out buffer) -> V staging = 2 ds_write_b128 (was 16
//     scalar b16 swizzled writes) and linear conflict-free bV reads.
// Keeps R11's LPT snake remap + T14 register prefetch + setprio.
// ws (bf16): qh[3145728] kh[3145728] vh[3145728] wt[4*589824] = 23.6 MB.
// vht (6.3 MB) lives in d_out (12.6 MB), which gemm_o overwrites at the end.

#define NEGV (-10000.0f)

typedef __attribute__((ext_vector_type(8))) short v8s;
typedef __attribute__((ext_vector_type(4))) float v4f;
typedef __attribute__((ext_vector_type(8))) unsigned short v8u;
typedef __fp16 h2v __attribute__((ext_vector_type(2)));

__device__ __forceinline__ unsigned short f2bf(float f) {
  unsigned int u = __float_as_uint(f);
  u += 0x7FFFu + ((u >> 16) & 1u);   // RNE
  return (unsigned short)(u >> 16);
}

__device__ __forceinline__ int pkmax_f16(int a, int b) {
  int r;
  asm("v_pk_max_f16 %0, %1, %2" : "=v"(r) : "v"(a), "v"(b));
  return r;
}

// ---------------------------------------------------------------- W transpose
// W fp32 [k][n] -> Wt bf16 [n][k]; 4 matrices via z.
__global__ __launch_bounds__(256) void transpose_w(
    const float* __restrict__ w0, const float* __restrict__ w1,
    const float* __restrict__ w2, const float* __restrict__ w3,
    unsigned short* __restrict__ t0, unsigned short* __restrict__ t1,
    unsigned short* __restrict__ t2, unsigned short* __restrict__ t3) {
  const float* w; unsigned short* t;
  switch (blockIdx.z) {
    case 0: w = w0; t = t0; break;
    case 1: w = w1; t = t1; break;
    case 2: w = w2; t = t2; break;
    default: w = w3; t = t3; break;
  }
  __shared__ unsigned short tile[32][33];
  const int tx = threadIdx.x & 31, ty = threadIdx.x >> 5;
  const int x0 = blockIdx.x * 32, y0 = blockIdx.y * 32;
#pragma unroll
  for (int j = 0; j < 4; j++)
    tile[ty + j * 8][tx] = f2bf(w[(size_t)(y0 + ty + j * 8) * 768 + x0 + tx]);
  __syncthreads();
#pragma unroll
  for (int j = 0; j < 4; j++)
    t[(size_t)(x0 + ty + j * 8) * 768 + y0 + tx] = tile[tx][ty + j * 8];
}

// ---------------------------------------------------------------- V transpose
// vh head-major [bh][s=2048][d=64] -> vht [bh][d=64][s=2048] (bf16).
__global__ __launch_bounds__(256) void transpose_vh(
    const unsigned short* __restrict__ vh, unsigned short* __restrict__ vht) {
  __shared__ unsigned short tile[32][33];
  const size_t hoff = (size_t)blockIdx.z * 2048 * 64;
  const unsigned short* src = vh + hoff;
  unsigned short* dst = vht + hoff;
  const int s0 = blockIdx.x * 32, d0 = blockIdx.y * 32;
  const int tx = threadIdx.x & 31, ty = threadIdx.x >> 5;
#pragma unroll
  for (int j = 0; j < 4; j++)
    tile[ty + j * 8][tx] = src[(size_t)(s0 + ty + j * 8) * 64 + d0 + tx];
  __syncthreads();
#pragma unroll
  for (int j = 0; j < 4; j++)
    dst[(size_t)(d0 + ty + j * 8) * 2048 + s0 + tx] = tile[tx][ty + j * 8];
}

// ---------------------------------------------------------------- GEMM core
// 128x128 tile, 4 waves 2x2, 16x16x32 bf16 MFMA, BK=32.
template <bool ABF16HEAD, bool CF32ROW>
__device__ __forceinline__ void gemm_core(const void* __restrict__ A,
                                          const unsigned short* __restrict__ Wt,
                                          void* __restrict__ C) {
  const int tid = threadIdx.x;
  const int wave = tid >> 6, lane = tid & 63;
  const int quad = lane >> 4, l16 = lane & 15;
  const int wm = wave >> 1, wn = wave & 1;
  const int bm = blockIdx.x * 128, bn = blockIdx.y * 128;

  __shared__ __align__(16) unsigned short As[128 * 32];
  __shared__ __align__(16) unsigned short Bs[128 * 32];

  v4f acc[4][4];
#pragma unroll
  for (int i = 0; i < 4; i++)
#pragma unroll
    for (int j = 0; j < 4; j++) acc[i][j] = (v4f){0.f, 0.f, 0.f, 0.f};

  for (int kt = 0; kt < 24; kt++) {
    __syncthreads();
#pragma unroll
    for (int p = 0; p < 2; p++) {
      int idx = p * 256 + tid;
      int r = idx >> 2, c0 = (idx & 3) << 3;
      int rg = bm + r, c = kt * 32 + c0;
      if (ABF16HEAD) {
        size_t aoff = ((size_t)((rg >> 11) * 12 + (c >> 6)) * 2048 +
                       (rg & 2047)) * 64 + (c & 63);
        *(uint4*)&As[r * 32 + c0] =
            *(const uint4*)((const unsigned short*)A + aoff);
      } else {
        const float* Af = (const float*)A;
        size_t aoff = (size_t)rg * 768 + c;
        float4 x0 = *(const float4*)(Af + aoff);
        float4 x1 = *(const float4*)(Af + aoff + 4);
        v8u tmp;
        tmp[0] = f2bf(x0.x); tmp[1] = f2bf(x0.y);
        tmp[2] = f2bf(x0.z); tmp[3] = f2bf(x0.w);
        tmp[4] = f2bf(x1.x); tmp[5] = f2bf(x1.y);
        tmp[6] = f2bf(x1.z); tmp[7] = f2bf(x1.w);
        *(uint4*)&As[r * 32 + c0] = *(uint4*)&tmp;
      }
      *(uint4*)&Bs[r * 32 + c0] =
          *(const uint4*)&Wt[(size_t)(bn + r) * 768 + c];
    }
    __syncthreads();

    v8s aF[4], bF[4];
#pragma unroll
    for (int mt = 0; mt < 4; mt++)
      aF[mt] = *(const v8s*)&As[(wm * 64 + mt * 16 + l16) * 32 + quad * 8];
#pragma unroll
    for (int nt = 0; nt < 4; nt++)
      bF[nt] = *(const v8s*)&Bs[(wn * 64 + nt * 16 + l16) * 32 + quad * 8];
#pragma unroll
    for (int mt = 0; mt < 4; mt++)
#pragma unroll
      for (int nt = 0; nt < 4; nt++)
        acc[mt][nt] = __builtin_amdgcn_mfma_f32_16x16x32_bf16(
            aF[mt], bF[nt], acc[mt][nt], 0, 0, 0);
  }

#pragma unroll
  for (int mt = 0; mt < 4; mt++) {
#pragma unroll
    for (int i = 0; i < 4; i++) {
      int row = bm + wm * 64 + mt * 16 + quad * 4 + i;
#pragma unroll
      for (int nt = 0; nt < 4; nt++) {
        int col = bn + wn * 64 + nt * 16 + l16;
        if (CF32ROW) {
          ((float*)C)[(size_t)row * 768 + col] = acc[mt][nt][i];
        } else {
          size_t off = ((size_t)((row >> 11) * 12 + (col >> 6)) * 2048 +
                        (row & 2047)) * 64 + (col & 63);
          ((unsigned short*)C)[off] = f2bf(acc[mt][nt][i]);
        }
      }
    }
  }
}

__global__ __launch_bounds__(256) void gemm_qkv(
    const float* __restrict__ xq, const float* __restrict__ xk,
    const float* __restrict__ xv, const unsigned short* __restrict__ wqt,
    const unsigned short* __restrict__ wkt, const unsigned short* __restrict__ wvt,
    unsigned short* __restrict__ qh, unsigned short* __restrict__ kh,
    unsigned short* __restrict__ vh) {
  const float* A; const unsigned short* Wt; unsigned short* C;
  switch (blockIdx.z) {
    case 0: A = xq; Wt = wqt; C = qh; break;
    case 1: A = xk; Wt = wkt; C = kh; break;
    default: A = xv; Wt = wvt; C = vh; break;
  }
  gemm_core<false, false>((const void*)A, Wt, (void*)C);
}

__global__ __launch_bounds__(256) void gemm_o(
    const unsigned short* __restrict__ oat, const unsigned short* __restrict__ wot,
    float* __restrict__ out) {
  gemm_core<true, true>((const void*)oat, wot, (void*)out);
}

// ---------------------------------------------------------------- attention
// grid (32, 24) = 768 linear blocks; LPT snake remap (R11). 4 waves x 16
// q-rows. Causal tiles kt=0..qt always; future tiles only if some row's
// visible window was fully padded (bit-exact skip, see R10 note).
__global__ __launch_bounds__(256) void attn_kernel(
    const unsigned short* __restrict__ qh, const unsigned short* __restrict__ kh,
    const unsigned short* __restrict__ vht, const int* __restrict__ attn_mask,
    const int* __restrict__ mask_future, unsigned short* __restrict__ o) {
  const int S = 2048, HD = 64, NH = 12;

  const int nlin = blockIdx.x + 32 * blockIdx.y;
  const int m_ = nlin & 255, t_ = nlin >> 8;
  const int i_ = (t_ == 1) ? (511 - m_) : (t_ * 256 + m_);
  const int qt = 31 - i_ / 24;
  const int bh = i_ - (i_ / 24) * 24;
  const int b = bh / NH, h = bh % NH;

  const int tid = threadIdx.x;
  const int wave = tid >> 6, lane = tid & 63;
  const int quad = lane >> 4, l16 = lane & 15;

  __shared__ __align__(16) unsigned short Ks[64 * 72];
  __shared__ __align__(16) unsigned short Vt[64 * 72];   // Vt[d][k] (= V^T)
  __shared__ __align__(16) unsigned short Ps[4][16 * 72];
  __shared__ int Ms[64];
  __shared__ int s_flag;

  const size_t head_off = (size_t)(b * NH + h) * S * HD;
  const unsigned short* Kb = kh + head_off;
  const unsigned short* Vb = vht + head_off;   // [d=64][s=2048] per head

  const int mf = mask_future[0];
  if (tid == 0) s_flag = 0;

  const int qrowA = qt * 64 + wave * 16 + l16;
  v8s aQ[2];
  {
    const unsigned short* qp = qh + head_off + (size_t)qrowA * HD + quad * 8;
    aQ[0] = *(const v8s*)(qp);
    aQ[1] = *(const v8s*)(qp + 32);
  }
  const int qbase = qt * 64 + wave * 16 + quad * 4;

  float m_i[4];
  v4f accO[4], accL;
#pragma unroll
  for (int i = 0; i < 4; i++) m_i[i] = -1e30f;
  accL = (v4f){0.f, 0.f, 0.f, 0.f};
#pragma unroll
  for (int dt = 0; dt < 4; dt++) accO[dt] = (v4f){0.f, 0.f, 0.f, 0.f};

  v8s ones;   // bf16 1.0 in all 8 slots -> B-frag of all-ones for row-sum MFMA
#pragma unroll
  for (int j = 0; j < 8; j++) ones[j] = (short)0x3F80;

  const int kt_causal = mf ? qt : (S / 64 - 1);
  const int r0 = tid >> 3, c0s = (tid & 7) << 3;

  // T14 register prefetch state
  uint4 pk0, pk1, pv0, pv1;
  int pm = 0;
  bool have = false;

  auto prefetch = [&](int kt) {
    const uint4* srck = (const uint4*)(Kb + (size_t)kt * 64 * HD);
    pk0 = srck[tid];
    pk1 = srck[256 + tid];
    const unsigned short* vp = Vb + (size_t)r0 * S + kt * 64 + c0s;
    pv0 = *(const uint4*)vp;
    pv1 = *(const uint4*)(vp + (size_t)32 * S);
    if (tid < 64) pm = attn_mask[b * S + kt * 64 + tid];
  };

  auto stage = [&]() {
    *(uint4*)&Ks[r0 * 72 + c0s] = pk0;
    *(uint4*)&Ks[(r0 + 32) * 72 + c0s] = pk1;
    *(uint4*)&Vt[r0 * 72 + c0s] = pv0;
    *(uint4*)&Vt[(r0 + 32) * 72 + c0s] = pv1;
    if (tid < 64) Ms[tid] = pm;
  };

  for (int phase = 0; phase < 2; phase++) {
    int kt_lo, kt_hi;
    if (phase == 0) { kt_lo = 0; kt_hi = kt_causal; }
    else {
      bool need = (m_i[0] < -5000.f) || (m_i[1] < -5000.f) ||
                  (m_i[2] < -5000.f) || (m_i[3] < -5000.f);
      if (need) s_flag = 1;  // benign race (0->1)
      __syncthreads();
      if (!s_flag) break;
      kt_lo = kt_causal + 1; kt_hi = S / 64 - 1;
    }
    for (int kt = kt_lo; kt <= kt_hi; kt++) {
      if (!have) prefetch(kt);  // cold start of a phase only
      __syncthreads();          // prev compute done; LDS free
      stage();                  // regs -> LDS (K, V^T linear b128)
      __syncthreads();

      // issue NEXT tile's global loads; they drain under the compute below
      {
        int ktn = -1;
        if (kt < kt_hi) ktn = kt + 1;
        else if (phase == 0 && mf && kt_causal < S / 64 - 1)
          ktn = kt_causal + 1;
        if (ktn >= 0) { prefetch(ktn); have = true; }
        else have = false;
      }

      // S = Q K^T
      v4f sc[4];
      __builtin_amdgcn_s_setprio(1);
#pragma unroll
      for (int nt = 0; nt < 4; nt++) {
        const unsigned short* kp = &Ks[(nt * 16 + l16) * 72 + quad * 8];
        v8s b0 = *(const v8s*)kp;
        v8s b1 = *(const v8s*)(kp + 32);
        v4f z = (v4f){0.f, 0.f, 0.f, 0.f};
        z = __builtin_amdgcn_mfma_f32_16x16x32_bf16(aQ[0], b0, z, 0, 0, 0);
        z = __builtin_amdgcn_mfma_f32_16x16x32_bf16(aQ[1], b1, z, 0, 0, 0);
        sc[nt] = z;
      }
      __builtin_amdgcn_s_setprio(0);

      // scale + causal (additive) + padding (replace) — exact ref semantics
#pragma unroll
      for (int nt = 0; nt < 4; nt++) {
        int key = kt * 64 + nt * 16 + l16;
        bool pad = (Ms[nt * 16 + l16] == 0);
#pragma unroll
        for (int i = 0; i < 4; i++) {
          float v = sc[nt][i] * 0.125f;
          v += (mf && (key > qbase + i)) ? NEGV : 0.f;
          v = pad ? NEGV : v;
          sc[nt][i] = v;
        }
      }

      // row max: in-lane over nt, then packed-f16 xor-reduce across l16.
      // softmax is invariant to the exact m (only row-uniformity matters),
      // so f16-rounded max is safe; -10000 is exactly representable.
      float m4[4];
#pragma unroll
      for (int i = 0; i < 4; i++)
        m4[i] = fmaxf(fmaxf(sc[0][i], sc[1][i]), fmaxf(sc[2][i], sc[3][i]));
      union { h2v h; int v; } pk01, pk23;
      pk01.h = __builtin_amdgcn_cvt_pkrtz(m4[0], m4[1]);
      pk23.h = __builtin_amdgcn_cvt_pkrtz(m4[2], m4[3]);
      int v01 = pk01.v, v23 = pk23.v;
#pragma unroll
      for (int mk = 1; mk <= 8; mk <<= 1) {
        v01 = pkmax_f16(v01, __shfl_xor(v01, mk));
        v23 = pkmax_f16(v23, __shfl_xor(v23, mk));
      }
      union { int v; h2v h; } u01, u23;
      u01.v = v01; u23.v = v23;
      float mx[4] = {(float)u01.h[0], (float)u01.h[1],
                     (float)u23.h[0], (float)u23.h[1]};

#pragma unroll
      for (int i = 0; i < 4; i++) {
        float mnew = fmaxf(m_i[i], mx[i]);
        float alpha = __expf(m_i[i] - mnew);
        m_i[i] = mnew;
#pragma unroll
        for (int nt = 0; nt < 4; nt++)
          sc[nt][i] = __expf(sc[nt][i] - mnew);
#pragma unroll
        for (int dt = 0; dt < 4; dt++) accO[dt][i] *= alpha;
        accL[i] *= alpha;
      }

      // P: C-layout regs -> per-wave LDS -> A-layout frags
#pragma unroll
      for (int nt = 0; nt < 4; nt++)
#pragma unroll
        for (int i = 0; i < 4; i++)
          Ps[wave][(quad * 4 + i) * 72 + nt * 16 + l16] = f2bf(sc[nt][i]);

      __builtin_amdgcn_s_setprio(1);
#pragma unroll
      for (int ks = 0; ks < 2; ks++) {
        v8s aP = *(const v8s*)&Ps[wave][l16 * 72 + ks * 32 + quad * 8];
        // row-sum of P via MFMA (replaces 16 shuffle-adds): all cols equal
        accL = __builtin_amdgcn_mfma_f32_16x16x32_bf16(aP, ones, accL, 0, 0, 0);
#pragma unroll
        for (int dt = 0; dt < 4; dt++) {
          v8s bV = *(const v8s*)&Vt[(dt * 16 + l16) * 72 + ks * 32 + quad * 8];
          accO[dt] =
              __builtin_amdgcn_mfma_f32_16x16x32_bf16(aP, bV, accO[dt], 0, 0, 0);
        }
      }
      __builtin_amdgcn_s_setprio(0);
    }
    if (phase == 0) __syncthreads();  // all waves done before flag vote
  }

  // normalize + store O bf16 head-major over own Q region (in place)
#pragma unroll
  for (int i = 0; i < 4; i++) {
    float inv = 1.f / accL[i];
    int qr = qbase + i;
    size_t base = head_off + (size_t)qr * HD;
#pragma unroll
    for (int dt = 0; dt < 4; dt++)
      o[base + dt * 16 + l16] = f2bf(accO[dt][i] * inv);
  }
}

// ---------------------------------------------------------------- launch
extern "C" void kernel_launch(void* const* d_in, const int* in_sizes, int n_in,
                              void* d_out, int out_size, void* d_ws, size_t ws_size,
                              hipStream_t stream) {
  const float* q  = (const float*)d_in[0];
  const float* k  = (const float*)d_in[1];
  const float* v  = (const float*)d_in[2];
  const int* amask = (const int*)d_in[3];
  const float* Wq = (const float*)d_in[4];
  const float* Wk = (const float*)d_in[5];
  const float* Wv = (const float*)d_in[6];
  const float* Wo = (const float*)d_in[7];
  const int* mf  = (const int*)d_in[8];
  float* out = (float*)d_out;

  unsigned short* ws = (unsigned short*)d_ws;
  unsigned short* qh = ws;                  // O overwrites qh after attention
  unsigned short* kh = qh + 3145728;
  unsigned short* vh = kh + 3145728;
  unsigned short* wqt = vh + 3145728;
  unsigned short* wkt = wqt + 589824;
  unsigned short* wvt = wkt + 589824;
  unsigned short* wot = wvt + 589824;
  // vht (6.3 MB bf16) lives in d_out (12.6 MB) — dead until gemm_o overwrites.
  unsigned short* vht = (unsigned short*)d_out;

  transpose_w<<<dim3(24, 24, 4), 256, 0, stream>>>(Wq, Wk, Wv, Wo,
                                                   wqt, wkt, wvt, wot);
  gemm_qkv<<<dim3(32, 6, 3), 256, 0, stream>>>(q, k, v, wqt, wkt, wvt,
                                               qh, kh, vh);
  transpose_vh<<<dim3(64, 2, 24), 256, 0, stream>>>(vh, vht);
  attn_kernel<<<dim3(32, 24), 256, 0, stream>>>(qh, kh, vht, amask, mf, qh);
  gemm_o<<<dim3(32, 6), 256, 0, stream>>>(qh, wot, out);
}